// Round 11
// baseline (90.954 us; speedup 1.0000x reference)
//
#include <hip/hip_runtime.h>

// Problem constants (from reference)
constexpr int Ni = 4, Ci = 256, Hi = 256, Wi = 256;
constexpr int Bn = 512, PHn = 7, PWn = 7, SRn = 2;
constexpr float SCALEf = 0.25f;

constexpr int NBINS = PHn * PWn;   // 49
constexpr int NSY = PHn * SRn;     // 14 y samples
constexpr int NSX = PWn * SRn;     // 14 x samples
constexpr int NROWS = 2 * NSY;     // 28 staged rows (ylo/yhi per sample)
constexpr int W4 = 13;             // float4s per row (52 floats >= 3 + 48 span)
constexpr int LSTR = 56;           // LDS row stride floats: mult of 4 (16B align), %32!=0
constexpr int CCHUNK = 4;          // channels per block
constexpr int NCHUNKS = Ci / CCHUNK;  // 64
constexpr int PLANE = Hi * Wi;
constexpr size_t TOTF = (size_t)Ni * Ci * PLANE;   // total input floats

__global__ __launch_bounds__(256) void roialign_kernel(
    const float* __restrict__ input,
    const float* __restrict__ rois,
    float* __restrict__ out)
{
    // ---- chunk-major + XCD-aware decomposition (R4, proven) ----
    const int blk   = blockIdx.x;
    const int xcd   = blk & 7;
    const int idx   = blk >> 3;              // 0..4095
    const int chunk = xcd * 8 + (idx >> 9);  // 0..63
    const int b     = idx & 511;             // ROI id

    __shared__ float s_patch[CCHUNK][NROWS][LSTR];   // 25088 B -> 6 blocks/CU
    __shared__ int   s_gyo[NROWS];                   // premultiplied row offsets (gy*Wi)
    __shared__ float s_lyf[NSY];
    __shared__ int   s_yv[NSY];
    __shared__ int   s_xlo[NSX], s_xhi[NSX], s_xv[NSX];
    __shared__ float s_lxf[NSX];
    __shared__ int   s_bidx, s_x0a;

    const int t = threadIdx.x;

    // ---- Phase A: per-ROI sample indices/weights (mirrors _interp_1d) ----
    if (t < NSY + NSX) {
        const float r0  = __builtin_nontemporal_load(&rois[b * 5 + 0]);
        const float rx1 = __builtin_nontemporal_load(&rois[b * 5 + 1]);
        const float ry1 = __builtin_nontemporal_load(&rois[b * 5 + 2]);
        const float rx2 = __builtin_nontemporal_load(&rois[b * 5 + 3]);
        const float ry2 = __builtin_nontemporal_load(&rois[b * 5 + 4]);
        const float x1 = rx1 * SCALEf - 0.5f;
        const float y1 = ry1 * SCALEf - 0.5f;
        const float x2 = rx2 * SCALEf - 0.5f;
        const float y2 = ry2 * SCALEf - 0.5f;
        const float bin_w = (x2 - x1) / (float)PWn;
        const float bin_h = (y2 - y1) / (float)PHn;
        if (t == 0) s_bidx = (int)r0;

        const bool isY = (t < NSY);
        const int  s   = isY ? t : (t - NSY);
        const int  p   = s >> 1;            // / SRn
        const int  i   = s & 1;             // % SRn
        const float off   = ((float)i + 0.5f) / (float)SRn;
        const float start = isY ? y1 : x1;
        const float binsz = isY ? bin_h : bin_w;
        const float c     = start + ((float)p + off) * binsz;
        const int   size  = isY ? Hi : Wi;

        const bool  valid = (c >= -1.0f) && (c <= (float)size);
        const float cc    = fmaxf(c, 0.0f);
        const float lo_f  = floorf(cc);
        int lo = min((int)lo_f, size - 1);
        int hi = min(lo + 1, size - 1);
        const float c_adj = (lo_f >= (float)(size - 1)) ? (float)(size - 1) : cc;
        const float frac  = c_adj - (float)lo;

        if (isY) {
            s_gyo[2 * s]     = lo * Wi;
            s_gyo[2 * s + 1] = hi * Wi;
            s_lyf[s] = frac;
            s_yv[s]  = valid ? 1 : 0;
        } else {
            s_xlo[s] = lo; s_xhi[s] = hi; s_lxf[s] = frac; s_xv[s] = valid ? 1 : 0;
            if (s == 0) s_x0a = lo & ~3;   // aligned window base
        }
    }
    __syncthreads();

    const int bidx = s_bidx;
    const int x0a  = s_x0a;

    // ---- Phase B: float4 row staging (13 float4/row, all rows, 4 channels) ----
    // threads t<247: i4 = t%13 (col4), rr = t/13 (0..18); rows rr, rr+19
    {
        const int i4 = t % W4;
        const int rr = t / W4;
        if (rr < 19) {
            const size_t base = (size_t)bidx * Ci * PLANE
                              + (size_t)(chunk * CCHUNK) * PLANE + x0a + (i4 << 2);
            const int gyo0 = s_gyo[rr];
            const int gyo1 = (rr + 19 < NROWS) ? s_gyo[rr + 19] : 0;
            #pragma unroll
            for (int cl = 0; cl < CCHUNK; ++cl) {
                const size_t pb = base + (size_t)cl * PLANE;
                // flat end-of-buffer clamp (only last row of last plane could spill)
                const float4 v0 = *(const float4*)(input + min(pb + gyo0, TOTF - 4));
                *(float4*)&s_patch[cl][rr][i4 << 2] = v0;
                if (rr + 19 < NROWS) {
                    const float4 v1 = *(const float4*)(input + min(pb + gyo1, TOTF - 4));
                    *(float4*)&s_patch[cl][rr + 19][i4 << 2] = v1;
                }
            }
        }
    }
    __syncthreads();

    // ---- Phase C: compute bins from LDS — single shot (196 <= 256 threads) ----
    if (t < CCHUNK * NBINS) {
        const int cl  = t / NBINS;
        const int bin = t - cl * NBINS;
        const int ph  = bin / PWn;
        const int pw  = bin - ph * PWn;

        float acc = 0.0f;
        #pragma unroll
        for (int iy = 0; iy < SRn; ++iy) {
            const int   sy  = ph * SRn + iy;
            const int   rlo = 2 * sy;
            const float ly  = s_lyf[sy];
            const float hy  = 1.0f - ly;
            const int   vy  = s_yv[sy];
            #pragma unroll
            for (int ix = 0; ix < SRn; ++ix) {
                const int   sx  = pw * SRn + ix;
                const int   dxl = s_xlo[sx] - x0a;
                const int   dxh = s_xhi[sx] - x0a;
                const float lx  = s_lxf[sx];
                const float hx  = 1.0f - lx;
                const float v11 = s_patch[cl][rlo    ][dxl];
                const float v12 = s_patch[cl][rlo    ][dxh];
                const float v21 = s_patch[cl][rlo + 1][dxl];
                const float v22 = s_patch[cl][rlo + 1][dxh];
                const float v   = hy * (hx * v11 + lx * v12) + ly * (hx * v21 + lx * v22);
                acc += (vy & s_xv[sx]) ? v : 0.0f;
            }
        }
        // Nontemporal: output is write-once, never re-read -> keep L2 for input
        __builtin_nontemporal_store(acc * (1.0f / (SRn * SRn)),
            &out[((size_t)b * Ci + chunk * CCHUNK) * NBINS + t]);
    }
}

extern "C" void kernel_launch(void* const* d_in, const int* in_sizes, int n_in,
                              void* d_out, int out_size, void* d_ws, size_t ws_size,
                              hipStream_t stream) {
    const float* input = (const float*)d_in[0];
    const float* rois  = (const float*)d_in[1];
    float* out = (float*)d_out;

    const int grid = Bn * NCHUNKS;  // 512 * 64 = 32768 blocks
    roialign_kernel<<<grid, 256, 0, stream>>>(input, rois, out);
}

// Round 12
// 85.004 us; speedup vs baseline: 1.0700x; 1.0700x over previous
//
#include <hip/hip_runtime.h>

// Problem constants (from reference)
constexpr int Ni = 4, Ci = 256, Hi = 256, Wi = 256;
constexpr int Bn = 512, PHn = 7, PWn = 7, SRn = 2;
constexpr float SCALEf = 0.25f;

constexpr int NBINS = PHn * PWn;   // 49
constexpr int NSY = PHn * SRn;     // 14 y samples
constexpr int NSX = PWn * SRn;     // 14 x samples
constexpr int NROWS = 2 * NSY;     // 28 staged rows (ylo/yhi per sample)
constexpr int W4 = 13;             // max float4s per row (covers 3 + 48 span)
constexpr int LSTR = 52;           // LDS row stride floats: mult of 4 (16B align), period-8 banks
constexpr int CCHUNK = 4;          // channels per block
constexpr int NCHUNKS = Ci / CCHUNK;  // 64
constexpr int PLANE = Hi * Wi;
constexpr size_t TOTF = (size_t)Ni * Ci * PLANE;   // total input floats

__global__ __launch_bounds__(256) void roialign_kernel(
    const float* __restrict__ input,
    const float* __restrict__ rois,
    float* __restrict__ out)
{
    // ---- chunk-major + XCD-aware decomposition (R4, proven) ----
    const int blk   = blockIdx.x;
    const int xcd   = blk & 7;
    const int idx   = blk >> 3;              // 0..4095
    const int chunk = xcd * 8 + (idx >> 9);  // 0..63
    const int b     = idx & 511;             // ROI id

    __shared__ float s_patch[CCHUNK][NROWS][LSTR];   // 23296 B -> 6 blocks/CU
    __shared__ int   s_gyo[NROWS];                   // premultiplied row offsets (gy*Wi)
    __shared__ float s_lyf[NSY];
    __shared__ int   s_yv[NSY];
    __shared__ int   s_xlo[NSX], s_xhi[NSX], s_xv[NSX];
    __shared__ float s_lxf[NSX];
    __shared__ int   s_bidx, s_x0a, s_n4;

    const int t = threadIdx.x;

    // ---- Phase A: per-ROI sample indices/weights (mirrors _interp_1d) ----
    if (t < NSY + NSX) {
        const float r0  = __builtin_nontemporal_load(&rois[b * 5 + 0]);
        const float rx1 = __builtin_nontemporal_load(&rois[b * 5 + 1]);
        const float ry1 = __builtin_nontemporal_load(&rois[b * 5 + 2]);
        const float rx2 = __builtin_nontemporal_load(&rois[b * 5 + 3]);
        const float ry2 = __builtin_nontemporal_load(&rois[b * 5 + 4]);
        const float x1 = rx1 * SCALEf - 0.5f;
        const float y1 = ry1 * SCALEf - 0.5f;
        const float x2 = rx2 * SCALEf - 0.5f;
        const float y2 = ry2 * SCALEf - 0.5f;
        const float bin_w = (x2 - x1) / (float)PWn;
        const float bin_h = (y2 - y1) / (float)PHn;
        if (t == 0) s_bidx = (int)r0;

        const bool isY = (t < NSY);
        const int  s   = isY ? t : (t - NSY);
        const int  p   = s >> 1;            // / SRn
        const int  i   = s & 1;             // % SRn
        const float off   = ((float)i + 0.5f) / (float)SRn;
        const float start = isY ? y1 : x1;
        const float binsz = isY ? bin_h : bin_w;
        const float c     = start + ((float)p + off) * binsz;
        const int   size  = isY ? Hi : Wi;

        const bool  valid = (c >= -1.0f) && (c <= (float)size);
        const float cc    = fmaxf(c, 0.0f);
        const float lo_f  = floorf(cc);
        int lo = min((int)lo_f, size - 1);
        int hi = min(lo + 1, size - 1);
        const float c_adj = (lo_f >= (float)(size - 1)) ? (float)(size - 1) : cc;
        const float frac  = c_adj - (float)lo;

        if (isY) {
            s_gyo[2 * s]     = lo * Wi;
            s_gyo[2 * s + 1] = hi * Wi;
            s_lyf[s] = frac;
            s_yv[s]  = valid ? 1 : 0;
        } else {
            s_xlo[s] = lo; s_xhi[s] = hi; s_lxf[s] = frac; s_xv[s] = valid ? 1 : 0;
            if (s == 0) s_x0a = lo & ~3;   // aligned window base
            if (s == NSX - 1) {
                // x0a is a pure function of the ROI: recompute locally (single
                // barrier). xs monotone -> x0 = lo of sample 0, xhi_max = hi.
                const float c0  = x1 + 0.25f * bin_w;
                const float cc0 = fmaxf(c0, 0.0f);
                const int   lo0 = min((int)floorf(cc0), Wi - 1);
                const int   x0a = lo0 & ~3;
                // float4 count covering [x0a .. hi]: <= 13
                s_n4 = ((hi - x0a) >> 2) + 1;
            }
        }
    }
    __syncthreads();

    const int bidx = s_bidx;
    const int x0a  = s_x0a;
    const int n4   = s_n4;

    // ---- Phase B: float4 staging, EXACT width (n4 float4s per row) ----
    // threads t<247: i4 = t%13 (col4), rr = t/13 (0..18); rows rr and rr+19
    {
        const int i4 = t % W4;
        const int rr = t / W4;
        if (rr < 19 && i4 < n4) {
            const size_t base = (size_t)bidx * Ci * PLANE
                              + (size_t)(chunk * CCHUNK) * PLANE + x0a + (i4 << 2);
            const int gyo0 = s_gyo[rr];
            const int gyo1 = (rr + 19 < NROWS) ? s_gyo[rr + 19] : 0;
            #pragma unroll
            for (int cl = 0; cl < CCHUNK; ++cl) {
                const size_t pb = base + (size_t)cl * PLANE;
                // flat end-of-tensor clamp (row spill stays in-plane and is
                // never consumed; only absolute buffer end needs the guard)
                const float4 v0 = *(const float4*)(input + min(pb + gyo0, TOTF - 4));
                *(float4*)&s_patch[cl][rr][i4 << 2] = v0;
                if (rr + 19 < NROWS) {
                    const float4 v1 = *(const float4*)(input + min(pb + gyo1, TOTF - 4));
                    *(float4*)&s_patch[cl][rr + 19][i4 << 2] = v1;
                }
            }
        }
    }
    __syncthreads();

    // ---- Phase C: compute bins from LDS — single shot (196 <= 256 threads) ----
    if (t < CCHUNK * NBINS) {
        const int cl  = t / NBINS;
        const int bin = t - cl * NBINS;
        const int ph  = bin / PWn;
        const int pw  = bin - ph * PWn;

        float acc = 0.0f;
        #pragma unroll
        for (int iy = 0; iy < SRn; ++iy) {
            const int   sy  = ph * SRn + iy;
            const int   rlo = 2 * sy;
            const float ly  = s_lyf[sy];
            const float hy  = 1.0f - ly;
            const int   vy  = s_yv[sy];
            #pragma unroll
            for (int ix = 0; ix < SRn; ++ix) {
                const int   sx  = pw * SRn + ix;
                const int   dxl = s_xlo[sx] - x0a;
                const int   dxh = s_xhi[sx] - x0a;
                const float lx  = s_lxf[sx];
                const float hx  = 1.0f - lx;
                const float v11 = s_patch[cl][rlo    ][dxl];
                const float v12 = s_patch[cl][rlo    ][dxh];
                const float v21 = s_patch[cl][rlo + 1][dxl];
                const float v22 = s_patch[cl][rlo + 1][dxh];
                const float v   = hy * (hx * v11 + lx * v12) + ly * (hx * v21 + lx * v22);
                acc += (vy & s_xv[sx]) ? v : 0.0f;
            }
        }
        // Nontemporal: output is write-once, never re-read -> keep L2 for input
        __builtin_nontemporal_store(acc * (1.0f / (SRn * SRn)),
            &out[((size_t)b * Ci + chunk * CCHUNK) * NBINS + t]);
    }
}

extern "C" void kernel_launch(void* const* d_in, const int* in_sizes, int n_in,
                              void* d_out, int out_size, void* d_ws, size_t ws_size,
                              hipStream_t stream) {
    const float* input = (const float*)d_in[0];
    const float* rois  = (const float*)d_in[1];
    float* out = (float*)d_out;

    const int grid = Bn * NCHUNKS;  // 512 * 64 = 32768 blocks
    roialign_kernel<<<grid, 256, 0, stream>>>(input, rois, out);
}

// Round 13
// 83.591 us; speedup vs baseline: 1.0881x; 1.0169x over previous
//
#include <hip/hip_runtime.h>

// Problem constants (from reference)
constexpr int Ni = 4, Ci = 256, Hi = 256, Wi = 256;
constexpr int Bn = 512, PHn = 7, PWn = 7, SRn = 2;
constexpr float SCALEf = 0.25f;

constexpr int NBINS = PHn * PWn;   // 49
constexpr int NSY = PHn * SRn;     // 14 y samples
constexpr int NSX = PWn * SRn;     // 14 x samples
constexpr int NROWS = 2 * NSY;     // 28 staged rows (ylo/yhi per sample)
constexpr int WSTG = 48;           // max staged row width (6.5*bin_w+2 <= 47)
constexpr int WPAD = 49;           // padded LDS stride (odd -> spreads banks)
constexpr int CCHUNK = 4;          // channels per block (22KB LDS -> 7 blocks/CU)
constexpr int NCHUNKS = Ci / CCHUNK;  // 64
constexpr int PLANE = Hi * Wi;

__global__ __launch_bounds__(256) void roialign_kernel(
    const float* __restrict__ input,
    const float* __restrict__ rois,
    float* __restrict__ out)
{
    // ---- chunk-major + XCD-aware decomposition (R4, proven) ----
    const int blk   = blockIdx.x;
    const int xcd   = blk & 7;
    const int idx   = blk >> 3;              // 0..4095
    const int chunk = xcd * 8 + (idx >> 9);  // 0..63
    const int b     = idx & 511;             // ROI id

    __shared__ float s_patch[CCHUNK][NROWS][WPAD];   // 21952 B
    __shared__ int   s_gyo[NROWS];                   // premultiplied row offsets (gy*Wi)
    __shared__ float s_lyf[NSY];
    __shared__ int   s_yv[NSY];
    __shared__ int   s_xlo[NSX], s_xhi[NSX], s_xv[NSX];
    __shared__ float s_lxf[NSX];
    __shared__ int   s_bidx, s_x0, s_xspan;

    const int t = threadIdx.x;

    // ---- Phase A: per-ROI sample indices/weights (mirrors _interp_1d) ----
    if (t < NSY + NSX) {
        const float r0  = __builtin_nontemporal_load(&rois[b * 5 + 0]);
        const float rx1 = __builtin_nontemporal_load(&rois[b * 5 + 1]);
        const float ry1 = __builtin_nontemporal_load(&rois[b * 5 + 2]);
        const float rx2 = __builtin_nontemporal_load(&rois[b * 5 + 3]);
        const float ry2 = __builtin_nontemporal_load(&rois[b * 5 + 4]);
        const float x1 = rx1 * SCALEf - 0.5f;
        const float y1 = ry1 * SCALEf - 0.5f;
        const float x2 = rx2 * SCALEf - 0.5f;
        const float y2 = ry2 * SCALEf - 0.5f;
        const float bin_w = (x2 - x1) / (float)PWn;
        const float bin_h = (y2 - y1) / (float)PHn;
        if (t == 0) s_bidx = (int)r0;

        const bool isY = (t < NSY);
        const int  s   = isY ? t : (t - NSY);
        const int  p   = s >> 1;            // / SRn
        const int  i   = s & 1;             // % SRn
        const float off   = ((float)i + 0.5f) / (float)SRn;
        const float start = isY ? y1 : x1;
        const float binsz = isY ? bin_h : bin_w;
        const float c     = start + ((float)p + off) * binsz;
        const int   size  = isY ? Hi : Wi;

        const bool  valid = (c >= -1.0f) && (c <= (float)size);
        const float cc    = fmaxf(c, 0.0f);
        const float lo_f  = floorf(cc);
        int lo = min((int)lo_f, size - 1);
        int hi = min(lo + 1, size - 1);
        const float c_adj = (lo_f >= (float)(size - 1)) ? (float)(size - 1) : cc;
        const float frac  = c_adj - (float)lo;

        if (isY) {
            s_gyo[2 * s]     = lo * Wi;
            s_gyo[2 * s + 1] = hi * Wi;
            s_lyf[s] = frac;
            s_yv[s]  = valid ? 1 : 0;
        } else {
            s_xlo[s] = lo; s_xhi[s] = hi; s_lxf[s] = frac; s_xv[s] = valid ? 1 : 0;
            if (s == 0) s_x0 = lo;
            if (s == NSX - 1) {
                // x0 is a pure function of roi values: recompute locally to
                // avoid a second barrier. xs monotone -> x0 = lo of sample 0.
                const float c0  = x1 + 0.25f * bin_w;
                const float cc0 = fmaxf(c0, 0.0f);
                const int   lo0 = min((int)floorf(cc0), Wi - 1);
                s_xspan = hi - lo0 + 1;      // <= 48
            }
        }
    }
    __syncthreads();

    const int bidx  = s_bidx;
    const int x0    = s_x0;
    const int xspan = s_xspan;

    // ---- Phase B: coalesced row staging, exact width, affine indexing ----
    {
        const int i  = t % WSTG;
        const int rr = t / WSTG;
        if (t < 240 && i < xspan) {
            const int gxc = min(x0 + i, Wi - 1);
            int gyo[6];
            #pragma unroll
            for (int k = 0; k < 6; ++k) {
                const int r = rr + 5 * k;
                gyo[k] = (r < NROWS) ? s_gyo[r] : 0;
            }
            const float* base = input + (size_t)bidx * Ci * PLANE
                              + (size_t)(chunk * CCHUNK) * PLANE + gxc;
            #pragma unroll
            for (int cl = 0; cl < CCHUNK; ++cl) {
                const float* plane = base + (size_t)cl * PLANE;
                #pragma unroll
                for (int k = 0; k < 6; ++k) {
                    const int r = rr + 5 * k;
                    if (r < NROWS) {
                        s_patch[cl][r][i] = plane[gyo[k]];
                    }
                }
            }
        }
    }
    __syncthreads();

    // ---- Phase C: compute bins from LDS — single shot (196 <= 256 threads) ----
    if (t < CCHUNK * NBINS) {
        const int cl  = t / NBINS;
        const int bin = t - cl * NBINS;
        const int ph  = bin / PWn;
        const int pw  = bin - ph * PWn;

        float acc = 0.0f;
        #pragma unroll
        for (int iy = 0; iy < SRn; ++iy) {
            const int   sy  = ph * SRn + iy;
            const int   rlo = 2 * sy;
            const float ly  = s_lyf[sy];
            const float hy  = 1.0f - ly;
            const int   vy  = s_yv[sy];
            #pragma unroll
            for (int ix = 0; ix < SRn; ++ix) {
                const int   sx  = pw * SRn + ix;
                const int   dxl = s_xlo[sx] - x0;
                const int   dxh = s_xhi[sx] - x0;
                const float lx  = s_lxf[sx];
                const float hx  = 1.0f - lx;
                const float v11 = s_patch[cl][rlo    ][dxl];
                const float v12 = s_patch[cl][rlo    ][dxh];
                const float v21 = s_patch[cl][rlo + 1][dxl];
                const float v22 = s_patch[cl][rlo + 1][dxh];
                const float v   = hy * (hx * v11 + lx * v12) + ly * (hx * v21 + lx * v22);
                acc += (vy & s_xv[sx]) ? v : 0.0f;
            }
        }
        // Nontemporal: output is write-once, never re-read -> keep L2 for input
        __builtin_nontemporal_store(acc * (1.0f / (SRn * SRn)),
            &out[((size_t)b * Ci + chunk * CCHUNK) * NBINS + t]);
    }
}

extern "C" void kernel_launch(void* const* d_in, const int* in_sizes, int n_in,
                              void* d_out, int out_size, void* d_ws, size_t ws_size,
                              hipStream_t stream) {
    const float* input = (const float*)d_in[0];
    const float* rois  = (const float*)d_in[1];
    float* out = (float*)d_out;

    const int grid = Bn * NCHUNKS;  // 512 * 64 = 32768 blocks
    roialign_kernel<<<grid, 256, 0, stream>>>(input, rois, out);
}